// Round 2
// baseline (268.671 us; speedup 1.0000x reference)
//
#include <hip/hip_runtime.h>
#include <climits>

// StreamingRhythmProjector: B=4096 rows x U=2048 units, one block per row.
// Memory-bound: 6x f32/i32 (B,U) reads (192 MiB) + 3x f32 (B,U) writes (96 MiB).

constexpr int UNITS = 2048;
constexpr int BLOCK = 256;   // 4 waves; each thread owns 8 elements (2x float4)

static __device__ __forceinline__ float waveSum(float v) {
#pragma unroll
  for (int off = 32; off > 0; off >>= 1) v += __shfl_down(v, off, 64);
  return v;
}
static __device__ __forceinline__ int waveMin(int v) {
#pragma unroll
  for (int off = 32; off > 0; off >>= 1) v = min(v, __shfl_down(v, off, 64));
  return v;
}

__global__ __launch_bounds__(BLOCK) void rhythm_kernel(
    const float* __restrict__ dur_anchor,    // [B,U]
    const float* __restrict__ unit_mask,     // [B,U] prefix mask (0/1)
    const float* __restrict__ speech_budget, // [B]
    const float* __restrict__ pause_budget,  // [B]
    const float* __restrict__ dur_logratio,  // [B,U]
    const float* __restrict__ pause_weight,  // [B,U]
    const float* __restrict__ boundary,      // [B,U]
    const float* __restrict__ phase_ptr,     // [B]
    const float* __restrict__ backlog,       // [B]
    const float* __restrict__ clock_delta,   // [B]
    const int*   __restrict__ commit_front,  // [B]
    const int*   __restrict__ open_run,      // [B,U]
    float* __restrict__ out,                 // f32, 3*B*U + 4*B
    int B) {
  const int row = blockIdx.x;
  const int t = threadIdx.x;
  const size_t base = (size_t)row * UNITS;

  // ---- pass 1: load everything once, keep per-element state in registers ----
  float sv_src[8];  // raw dur_anchor_src (for src_prefix range sum)
  float sv_sr[8];   // speech_raw (already masked)
  float sv_sc[8];   // scores (already masked)
  float sv_m[8];    // mask (for pause fallback + effective)

  float sum_sr = 0.f, sum_sc = 0.f, sum_m = 0.f;
  int min_open = INT_MAX;

#pragma unroll
  for (int c = 0; c < 2; ++c) {
    const int e0 = c * 1024 + 4 * t;
    const float4 a4 = *(const float4*)(dur_anchor  + base + e0);
    const float4 m4 = *(const float4*)(unit_mask   + base + e0);
    const float4 l4 = *(const float4*)(dur_logratio + base + e0);
    const float4 p4 = *(const float4*)(pause_weight + base + e0);
    const float4 b4 = *(const float4*)(boundary     + base + e0);
    const int4   o4 = *(const int4*)(open_run      + base + e0);
    const float av[4] = {a4.x, a4.y, a4.z, a4.w};
    const float mv[4] = {m4.x, m4.y, m4.z, m4.w};
    const float lv[4] = {l4.x, l4.y, l4.z, l4.w};
    const float pv[4] = {p4.x, p4.y, p4.z, p4.w};
    const float bv[4] = {b4.x, b4.y, b4.z, b4.w};
    const int   ov[4] = {o4.x, o4.y, o4.z, o4.w};
#pragma unroll
    for (int j = 0; j < 4; ++j) {
      const int k = c * 4 + j;
      const float m = mv[j];
      const float a = fmaxf(av[j], 1.0f);                       // MIN_SPEECH_FRAMES
      const float bse = a * __expf(lv[j]);
      const float sr = fmaxf(fminf(bse, 3.0f * a), 1.0f) * m;   // MAX_SPEECH_EXPAND
      const float sc = fmaxf(pv[j], 0.0f) * (0.5f + bv[j]) * m;
      sv_src[k] = av[j];
      sv_sr[k] = sr;
      sv_sc[k] = sc;
      sv_m[k] = m;
      sum_sr += sr;
      sum_sc += sc;
      sum_m += m;
      // prefix mask => (idx < visible) <=> mask == 1
      if (ov[j] > 0 && m > 0.5f) min_open = min(min_open, e0 + j);
    }
  }

  // ---- block reduction 1: totals + first open index ----
  const int wv = t >> 6, ln = t & 63;
  __shared__ float sf[3][4];
  __shared__ int si[4];
  __shared__ float sh_sscale, sh_pscale, sh_fb;
  __shared__ int sh_commit, sh_prev, sh_usefb;

  const float r0 = waveSum(sum_sr);
  const float r1 = waveSum(sum_sc);
  const float r2 = waveSum(sum_m);
  const int ri = waveMin(min_open);
  if (ln == 0) { sf[0][wv] = r0; sf[1][wv] = r1; sf[2][wv] = r2; si[wv] = ri; }
  __syncthreads();

  if (t == 0) {
    const float ts = sf[0][0] + sf[0][1] + sf[0][2] + sf[0][3];
    const float tc = sf[1][0] + sf[1][1] + sf[1][2] + sf[1][3];
    const float tm = sf[2][0] + sf[2][1] + sf[2][2] + sf[2][3];
    const int mo = min(min(si[0], si[1]), min(si[2], si[3]));

    const int visible = (int)(tm + 0.5f);                 // exact: integer-valued f32
    const int closed = (mo == INT_MAX) ? visible : mo;
    const int relcap = max(visible - 2, 0);               // TAIL_HOLD_UNITS
    int cand = min(relcap, closed);
    const int prev = commit_front[row];
    const int bidx = min(max(cand - 1, 0), UNITS - 1);
    const float bval = boundary[base + bidx];             // L1/L2 hit (row just read)
    if (cand > 0 && cand < visible && bval < 0.45f)       // BOUNDARY_COMMIT_THRESHOLD
      cand = max(prev, cand - 1);
    sh_commit = max(prev, cand);
    sh_prev = prev;

    sh_sscale = speech_budget[row] / fmaxf(ts, 1e-6f);
    const float pb = pause_budget[row];
    if (tc > 0.0f) {
      sh_usefb = 0; sh_pscale = pb / fmaxf(tc, 1e-6f); sh_fb = 0.f;
    } else {
      sh_usefb = 1; sh_pscale = 0.f; sh_fb = pb / fmaxf(tm, 1.0f);
    }
  }
  __syncthreads();

  const float sscale = sh_sscale;
  const float pscale = sh_pscale;
  const float fb = sh_fb;
  const int usefb = sh_usefb;
  const int commit = sh_commit;
  const int prev = sh_prev;

  // ---- pass 2: outputs from registers + range sums ----
  float* __restrict__ out_speech = out;
  float* __restrict__ out_pause  = out + (size_t)B * UNITS;
  float* __restrict__ out_eff    = out + 2 * (size_t)B * UNITS;

  float eff_rng = 0.f, src_rng = 0.f, eff_tot = 0.f;
#pragma unroll
  for (int c = 0; c < 2; ++c) {
    const int e0 = c * 1024 + 4 * t;
    float s_[4], p_[4], e_[4];
#pragma unroll
    for (int j = 0; j < 4; ++j) {
      const int k = c * 4 + j;
      const int idx = e0 + j;
      const float m = sv_m[k];
      const float speech = sv_sr[k] * sscale;               // sr already masked
      const float pause = usefb ? (m * fb) : (sv_sc[k] * pscale);
      const float eff = (speech + pause) * m;
      s_[j] = speech;
      p_[j] = pause;
      e_[j] = eff;
      eff_tot += eff;
      const bool inr = (idx >= prev) && (idx < commit);
      eff_rng += inr ? eff : 0.f;
      src_rng += inr ? sv_src[k] : 0.f;
    }
    *reinterpret_cast<float4*>(out_speech + base + e0) =
        make_float4(s_[0], s_[1], s_[2], s_[3]);
    *reinterpret_cast<float4*>(out_pause + base + e0) =
        make_float4(p_[0], p_[1], p_[2], p_[3]);
    *reinterpret_cast<float4*>(out_eff + base + e0) =
        make_float4(e_[0], e_[1], e_[2], e_[3]);
  }

  // ---- block reduction 2: range sums + effective total ----
  const float q0 = waveSum(eff_rng);
  const float q1 = waveSum(src_rng);
  const float q2 = waveSum(eff_tot);
  if (ln == 0) { sf[0][wv] = q0; sf[1][wv] = q1; sf[2][wv] = q2; }
  __syncthreads();

  if (t == 0) {
    const float execp = sf[0][0] + sf[0][1] + sf[0][2] + sf[0][3];
    const float srcp  = sf[1][0] + sf[1][1] + sf[1][2] + sf[1][3];
    const float etot  = sf[2][0] + sf[2][1] + sf[2][2] + sf[2][3];
    const bool adv = commit > prev;
    const float cd = clock_delta[row];
    const float nclock = adv ? (cd + (execp - srcp)) : cd;
    const float nback = adv ? fmaxf(nclock, 0.0f) : backlog[row];
    const float vt = fmaxf(etot, 1.0f);
    const float nphase =
        adv ? fminf(fmaxf(phase_ptr[row] + execp / vt, 0.0f), 1.0f) : phase_ptr[row];
    const size_t o = 3 * (size_t)B * UNITS;
    out[o + row] = (float)commit;                 // commit (int32 read back as f32)
    out[o + (size_t)B + row] = nphase;
    out[o + 2 * (size_t)B + row] = nback;
    out[o + 3 * (size_t)B + row] = nclock;
  }
}

extern "C" void kernel_launch(void* const* d_in, const int* in_sizes, int n_in,
                              void* d_out, int out_size, void* d_ws, size_t ws_size,
                              hipStream_t stream) {
  const int B = in_sizes[7];  // phase_ptr length
  rhythm_kernel<<<dim3(B), dim3(BLOCK), 0, stream>>>(
      (const float*)d_in[0],   // dur_anchor_src
      (const float*)d_in[1],   // unit_mask
      (const float*)d_in[2],   // speech_budget_win
      (const float*)d_in[3],   // pause_budget_win
      (const float*)d_in[4],   // dur_logratio_unit
      (const float*)d_in[5],   // pause_weight_unit
      (const float*)d_in[6],   // boundary_latent
      (const float*)d_in[7],   // phase_ptr
      (const float*)d_in[8],   // backlog
      (const float*)d_in[9],   // clock_delta
      (const int*)d_in[10],    // commit_frontier
      (const int*)d_in[11],    // open_run_mask
      (float*)d_out, B);
}